// Round 1
// baseline (558.944 us; speedup 1.0000x reference)
//
#include <hip/hip_runtime.h>

#define IN_DIM   8
#define IN_CAPS  1152
#define OUT_CAPS 10
#define OUT_DIM  16
#define BATCH    512

// butterfly sum across the 16-lane group (lanes share same (tid>>4))
__device__ __forceinline__ float red16(float v) {
  v += __shfl_xor(v, 1);
  v += __shfl_xor(v, 2);
  v += __shfl_xor(v, 4);
  v += __shfl_xor(v, 8);
  return v;
}

__device__ __forceinline__ float dot8(const float4* wp, float4 xa, float4 xb) {
  float4 wa = wp[0];
  float4 wb = wp[1];
  return wa.x * xa.x + wa.y * xa.y + wa.z * xa.z + wa.w * xa.w +
         wb.x * xb.x + wb.y * xb.y + wb.z * xb.z + wb.w * xb.w;
}

__global__ __launch_bounds__(256, 2) void digitcaps_kernel(
    const float* __restrict__ x, const float* __restrict__ W,
    float* __restrict__ out) {
  __shared__ float xs[IN_CAPS * IN_DIM];            // 36 KB: x[b]
  __shared__ float s1[OUT_CAPS * OUT_DIM];          // v after iter 1
  __shared__ float s2[OUT_CAPS * OUT_DIM];          // v after iter 2
  __shared__ float so[OUT_CAPS * OUT_DIM];          // final v

  const int b   = blockIdx.x;
  const int tid = threadIdx.x;
  const int grp = tid >> 4;    // 0..15, strides over c
  const int d   = tid & 15;    // out_dim lane

  // stage x[b] (9216 floats) coalesced
  const float4* xg  = (const float4*)(x + (size_t)b * (IN_CAPS * IN_DIM));
  float4*       xs4 = (float4*)xs;
  #pragma unroll
  for (int i = 0; i < (IN_CAPS * IN_DIM / 4) / 256; ++i)
    xs4[tid + i * 256] = xg[tid + i * 256];
  if (tid < OUT_CAPS * OUT_DIM) { s1[tid] = 0.f; s2[tid] = 0.f; so[tid] = 0.f; }
  __syncthreads();

  // ---------------- sweep 1: s1[o,d] = 0.1 * sum_c u_hat[o,c,d] -------------
  {
    float acc[OUT_CAPS];
    #pragma unroll
    for (int o = 0; o < OUT_CAPS; ++o) acc[o] = 0.f;
    for (int c = grp; c < IN_CAPS; c += 16) {
      const float4* xc = (const float4*)(xs + c * IN_DIM);
      float4 xa = xc[0], xb = xc[1];
      const float* wbase = W + (size_t)c * (OUT_DIM * IN_DIM) + d * IN_DIM;
      #pragma unroll
      for (int o = 0; o < OUT_CAPS; ++o) {
        const float4* wp = (const float4*)(wbase + (size_t)o * (IN_CAPS * OUT_DIM * IN_DIM));
        acc[o] += dot8(wp, xa, xb);
      }
    }
    #pragma unroll
    for (int o = 0; o < OUT_CAPS; ++o) {
      float v = acc[o];
      v += __shfl_xor(v, 16);
      v += __shfl_xor(v, 32);
      if ((tid & 63) < 16) atomicAdd(&s1[o * OUT_DIM + d], v * 0.1f);
    }
  }
  __syncthreads();

  // ------- sweep 2: uv1 = u_hat·s1, c2 = softmax_o(uv1), s2 = Σ c2·u_hat ----
  {
    float acc[OUT_CAPS];
    #pragma unroll
    for (int o = 0; o < OUT_CAPS; ++o) acc[o] = 0.f;
    for (int c = grp; c < IN_CAPS; c += 16) {
      const float4* xc = (const float4*)(xs + c * IN_DIM);
      float4 xa = xc[0], xb = xc[1];
      const float* wbase = W + (size_t)c * (OUT_DIM * IN_DIM) + d * IN_DIM;
      float uh[OUT_CAPS], lg[OUT_CAPS];
      #pragma unroll
      for (int o = 0; o < OUT_CAPS; ++o) {
        const float4* wp = (const float4*)(wbase + (size_t)o * (IN_CAPS * OUT_DIM * IN_DIM));
        uh[o] = dot8(wp, xa, xb);
        lg[o] = red16(uh[o] * s1[o * OUT_DIM + d]);   // uv1[o], all lanes have it
      }
      // softmax over o (redundant per lane, thread-local)
      float m = lg[0];
      #pragma unroll
      for (int o = 1; o < OUT_CAPS; ++o) m = fmaxf(m, lg[o]);
      float sum = 0.f;
      #pragma unroll
      for (int o = 0; o < OUT_CAPS; ++o) { lg[o] = __expf(lg[o] - m); sum += lg[o]; }
      float inv = 1.f / sum;
      #pragma unroll
      for (int o = 0; o < OUT_CAPS; ++o) acc[o] += uh[o] * (lg[o] * inv);
    }
    #pragma unroll
    for (int o = 0; o < OUT_CAPS; ++o) {
      float v = acc[o];
      v += __shfl_xor(v, 16);
      v += __shfl_xor(v, 32);
      if ((tid & 63) < 16) atomicAdd(&s2[o * OUT_DIM + d], v);
    }
  }
  __syncthreads();

  // -- sweep 3: b2 = u_hat·s1 + u_hat·s2, c3 = softmax, out = Σ c3·u_hat ----
  {
    float acc[OUT_CAPS];
    #pragma unroll
    for (int o = 0; o < OUT_CAPS; ++o) acc[o] = 0.f;
    for (int c = grp; c < IN_CAPS; c += 16) {
      const float4* xc = (const float4*)(xs + c * IN_DIM);
      float4 xa = xc[0], xb = xc[1];
      const float* wbase = W + (size_t)c * (OUT_DIM * IN_DIM) + d * IN_DIM;
      float uh[OUT_CAPS], lg[OUT_CAPS];
      #pragma unroll
      for (int o = 0; o < OUT_CAPS; ++o) {
        const float4* wp = (const float4*)(wbase + (size_t)o * (IN_CAPS * OUT_DIM * IN_DIM));
        uh[o] = dot8(wp, xa, xb);
        float p1 = uh[o] * s1[o * OUT_DIM + d];
        float p2 = uh[o] * s2[o * OUT_DIM + d];
        lg[o] = red16(p1) + red16(p2);                // uv1 + uv2
      }
      float m = lg[0];
      #pragma unroll
      for (int o = 1; o < OUT_CAPS; ++o) m = fmaxf(m, lg[o]);
      float sum = 0.f;
      #pragma unroll
      for (int o = 0; o < OUT_CAPS; ++o) { lg[o] = __expf(lg[o] - m); sum += lg[o]; }
      float inv = 1.f / sum;
      #pragma unroll
      for (int o = 0; o < OUT_CAPS; ++o) acc[o] += uh[o] * (lg[o] * inv);
    }
    #pragma unroll
    for (int o = 0; o < OUT_CAPS; ++o) {
      float v = acc[o];
      v += __shfl_xor(v, 16);
      v += __shfl_xor(v, 32);
      if ((tid & 63) < 16) atomicAdd(&so[o * OUT_DIM + d], v);
    }
  }
  __syncthreads();

  if (tid < OUT_CAPS * OUT_DIM)
    out[(size_t)b * (OUT_CAPS * OUT_DIM) + tid] = so[tid];
}

extern "C" void kernel_launch(void* const* d_in, const int* in_sizes, int n_in,
                              void* d_out, int out_size, void* d_ws, size_t ws_size,
                              hipStream_t stream) {
  const float* x = (const float*)d_in[0];
  const float* W = (const float*)d_in[1];
  float* out = (float*)d_out;
  digitcaps_kernel<<<BATCH, 256, 0, stream>>>(x, W, out);
}